// Round 7
// baseline (219.459 us; speedup 1.0000x reference)
//
#include <hip/hip_runtime.h>

// Problem constants
#define BB 2
#define TT 2048
#define CC 1024
#define NH 16
#define HD 64

typedef __attribute__((ext_vector_type(8))) short bf16x8;
typedef __attribute__((ext_vector_type(4))) float floatx4;
typedef __attribute__((ext_vector_type(16))) float floatx16;

__device__ __forceinline__ unsigned short f2bf(float f) {
    union { float f; unsigned int u; } v; v.f = f;
    unsigned int u = v.u;
    u = (u + 0x7fffu + ((u >> 16) & 1u)) >> 16;   // RNE
    return (unsigned short)u;
}
__device__ __forceinline__ float bf2f(unsigned short u) {
    return __uint_as_float((unsigned)u << 16);
}

typedef __attribute__((address_space(3))) unsigned char* lds_ptr_t;
typedef const __attribute__((address_space(1))) unsigned char* glob_ptr_t;
__device__ __forceinline__ void gll16(const void* g, void* l) {
    __builtin_amdgcn_global_load_lds((glob_ptr_t)g, (lds_ptr_t)l, 16, 0, 0);
}

// ---------------- fused cast fp32 -> bf16 + RoPE table build ----------------
__global__ __launch_bounds__(256) void cast_all_k(const float* __restrict__ x,
                                                  const float* __restrict__ wq,
                                                  const float* __restrict__ wk,
                                                  const float* __restrict__ wv,
                                                  const float* __restrict__ wo,
                                                  unsigned short* __restrict__ xb,
                                                  unsigned short* __restrict__ wqkvb,
                                                  unsigned short* __restrict__ wob,
                                                  float2* __restrict__ tabQ,
                                                  float2* __restrict__ tabK) {
    if (blockIdx.x >= 8192) {   // RoPE tables: 2048 t x 32 pairs
        int idx = (blockIdx.x - 8192) * 256 + threadIdx.x;   // 0..65535
        int t = idx >> 5, j = idx & 31;
        const float C1 = 0.41524101186092f;        // log2(10000)/32
        const float I2PI = 0.15915494309189535f;
        float rev = (float)t * (__builtin_amdgcn_exp2f(-(float)j * C1) * I2PI);
        rev -= floorf(rev);
        float ang = rev * 6.2831853071796f;
        float c = __cosf(ang), s = __sinf(ang);
        const float qs = 0.18033688011112f;        // (1/8)*log2(e), folded into Q table
        tabK[idx] = make_float2(c, s);
        tabQ[idx] = make_float2(c * qs, s * qs);
        return;
    }
    int i = blockIdx.x * 256 + threadIdx.x;   // float4 index
    const float* src;
    unsigned short* dst;
    if (i < 1048576) {
        src = x + (size_t)i * 4;
        dst = xb + (size_t)i * 4;
    } else {
        int w   = (i - 1048576) >> 18;        // 0..3
        int off = (i - 1048576) & 262143;
        const float* s0 = (w == 0) ? wq : (w == 1) ? wk : (w == 2) ? wv : wo;
        unsigned short* d0 = (w == 3) ? wob : (wqkvb + (size_t)w * 1048576);
        src = s0 + (size_t)off * 4;
        dst = d0 + (size_t)off * 4;
    }
    float4 v = *(const float4*)src;
    ushort4 o;
    o.x = f2bf(v.x); o.y = f2bf(v.y); o.z = f2bf(v.z); o.w = f2bf(v.w);
    *(ushort4*)dst = o;
}

// ---------------- out-proj GEMM: BK=64, XOR-swizzled LDS, XCD-swizzled grid ----------------
__global__ __launch_bounds__(256) void gemm128_k(const unsigned short* __restrict__ A,
                                                 const unsigned short* __restrict__ Bt,
                                                 float* __restrict__ C, int N, int K) {
    __shared__ __align__(16) unsigned short As[128][64];
    __shared__ __align__(16) unsigned short Bs[128][64];
    const int tid  = threadIdx.x;
    const int wave = tid >> 6;
    const int lane = tid & 63;
    const int quad = lane >> 4;
    const int l16  = lane & 15;
    const int sw   = l16 & 7;             // fragment-read XOR key
    const int wr = (wave >> 1) * 64;
    const int wc = (wave & 1) * 64;
    const int bid = blockIdx.x;
    const int xcd = bid & 7, sl = bid >> 3;          // sl 0..31
    const int row0 = (xcd * 4 + (sl >> 3)) * 128;
    const int col0 = (sl & 7) * 128;
    // staging: issue j stages rows [j*32 + wave*8 + (lane>>3)], phys granule lane&7,
    // sourcing logical granule (lane&7)^(lane>>3)  (LDS dest = wave base + lane*16)
    const int w8r = wave * 8 + (lane >> 3);
    const int cg  = ((lane & 7) ^ (lane >> 3)) * 8;  // global col (shorts)
    const int cl  = (lane & 7) * 8;                  // phys LDS col (shorts)

    const unsigned short* Ap = A  + (size_t)(row0 + w8r) * K + cg;
    const unsigned short* Bp = Bt + (size_t)(col0 + w8r) * K + cg;

    floatx4 acc[4][4];
    #pragma unroll
    for (int i = 0; i < 4; i++)
        #pragma unroll
        for (int j = 0; j < 4; j++) acc[i][j] = (floatx4){0.f, 0.f, 0.f, 0.f};

    for (int k0 = 0; k0 < K; k0 += 64) {
        __syncthreads();
        #pragma unroll
        for (int isu = 0; isu < 4; isu++) {
            gll16(Ap + (size_t)(isu * 32) * K + k0, &As[isu * 32 + w8r][cl]);
            gll16(Bp + (size_t)(isu * 32) * K + k0, &Bs[isu * 32 + w8r][cl]);
        }
        __syncthreads();
        #pragma unroll
        for (int kk = 0; kk < 2; kk++) {
            bf16x8 af[4], bfr[4];
            #pragma unroll
            for (int i = 0; i < 4; i++)
                af[i]  = *(const bf16x8*)&As[wr + 16 * i + l16][((kk * 4 + quad) ^ sw) * 8];
            #pragma unroll
            for (int j = 0; j < 4; j++)
                bfr[j] = *(const bf16x8*)&Bs[wc + 16 * j + l16][((kk * 4 + quad) ^ sw) * 8];
            #pragma unroll
            for (int i = 0; i < 4; i++)
                #pragma unroll
                for (int j = 0; j < 4; j++)
                    acc[i][j] = __builtin_amdgcn_mfma_f32_16x16x32_bf16(af[i], bfr[j], acc[i][j], 0, 0, 0);
        }
    }

    #pragma unroll
    for (int i = 0; i < 4; i++)
        #pragma unroll
        for (int j = 0; j < 4; j++)
            #pragma unroll
            for (int r = 0; r < 4; r++) {
                int row = row0 + wr + 16 * i + quad * 4 + r;
                int col = col0 + wc + 16 * j + l16;
                C[(size_t)row * N + col] = acc[i][j][r];
            }
}

// ---------------- QKV GEMM: BK=64, XOR-swizzled LDS, table-RoPE LDS-bounce epilogue ----------------
__global__ __launch_bounds__(256) void gemm_qkv_k(const unsigned short* __restrict__ A,
                                                  const unsigned short* __restrict__ Bt,
                                                  const float2* __restrict__ tabQ,
                                                  const float2* __restrict__ tabK,
                                                  unsigned short* __restrict__ Qb,
                                                  unsigned short* __restrict__ Kb,
                                                  unsigned short* __restrict__ Vb) {
    __shared__ __align__(16) unsigned short SMEM[128 * 128];   // 32 KB: As+Bs in loop, Eb in epilogue
    unsigned short (*As)[64] = (unsigned short(*)[64])SMEM;
    unsigned short (*Bs)[64] = (unsigned short(*)[64])(SMEM + 128 * 64);
    unsigned short (*Eb)[128] = (unsigned short(*)[128])SMEM;
    const int K = 1024;
    const int tid  = threadIdx.x;
    const int wave = tid >> 6;
    const int lane = tid & 63;
    const int quad = lane >> 4;
    const int l16  = lane & 15;
    const int sw   = l16 & 7;
    const int wr = (wave >> 1) * 64;
    const int wc = (wave & 1) * 64;
    const int bid = blockIdx.x;
    const int xcd = bid & 7, sl = bid >> 3;          // sl 0..95
    const int row0 = (xcd * 4 + sl / 24) * 128;
    const int col0 = (sl % 24) * 128;
    const int w8r = wave * 8 + (lane >> 3);
    const int cg  = ((lane & 7) ^ (lane >> 3)) * 8;
    const int cl  = (lane & 7) * 8;

    const unsigned short* Ap = A  + (size_t)(row0 + w8r) * K + cg;
    const unsigned short* Bp = Bt + (size_t)(col0 + w8r) * K + cg;

    floatx4 acc[4][4];
    #pragma unroll
    for (int i = 0; i < 4; i++)
        #pragma unroll
        for (int j = 0; j < 4; j++) acc[i][j] = (floatx4){0.f, 0.f, 0.f, 0.f};

    for (int k0 = 0; k0 < K; k0 += 64) {
        __syncthreads();
        #pragma unroll
        for (int isu = 0; isu < 4; isu++) {
            gll16(Ap + (size_t)(isu * 32) * K + k0, &As[isu * 32 + w8r][cl]);
            gll16(Bp + (size_t)(isu * 32) * K + k0, &Bs[isu * 32 + w8r][cl]);
        }
        __syncthreads();
        #pragma unroll
        for (int kk = 0; kk < 2; kk++) {
            bf16x8 af[4], bfr[4];
            #pragma unroll
            for (int i = 0; i < 4; i++)
                af[i]  = *(const bf16x8*)&As[wr + 16 * i + l16][((kk * 4 + quad) ^ sw) * 8];
            #pragma unroll
            for (int j = 0; j < 4; j++)
                bfr[j] = *(const bf16x8*)&Bs[wc + 16 * j + l16][((kk * 4 + quad) ^ sw) * 8];
            #pragma unroll
            for (int i = 0; i < 4; i++)
                #pragma unroll
                for (int j = 0; j < 4; j++)
                    acc[i][j] = __builtin_amdgcn_mfma_f32_16x16x32_bf16(af[i], bfr[j], acc[i][j], 0, 0, 0);
        }
    }

    // ---- Phase 1: acc -> Eb (bf16), XOR-granule swizzle (granule = 8 shorts, phys g = g ^ (row&15)) ----
    __syncthreads();
    #pragma unroll
    for (int i = 0; i < 4; i++)
        #pragma unroll
        for (int j = 0; j < 4; j++)
            #pragma unroll
            for (int r = 0; r < 4; r++) {
                int erow = wr + 16 * i + quad * 4 + r;
                int col  = wc + 16 * j + l16;
                int pcol = (((col >> 3) ^ (erow & 15)) << 3) | (col & 7);
                Eb[erow][pcol] = f2bf(acc[i][j][r]);
            }
    __syncthreads();

    // ---- Phase 2: row-wise readback, RoPE via table, coalesced stores ----
    const int row  = tid >> 1;            // 0..127
    const int half = tid & 1;
    const int grow = row0 + row;
    const int t    = grow & (TT - 1);
    const int bb   = grow >> 11;
    const int sect = col0 >> 10;                        // 0=Q,1=K,2=V
    const int hh   = ((col0 & 1023) >> 6) + half;       // head
    union { int4 q[8]; unsigned short u[64]; } raw;
    #pragma unroll
    for (int i = 0; i < 8; i++) {
        int pg = (half * 8 + i) ^ (row & 15);
        raw.q[i] = *(const int4*)&Eb[row][pg << 3];
    }
    size_t obase = ((size_t)(bb * NH + hh) * TT + t) * 64;
    if (sect == 2) {
        #pragma unroll
        for (int i = 0; i < 8; i++) *(int4*)(Vb + obase + 8 * i) = raw.q[i];
    } else {
        const float4* tab = (const float4*)((sect ? tabK : tabQ) + (size_t)t * 32);
        unsigned short* dst = sect ? Kb : Qb;
        union { int4 q[8]; unsigned short u[64]; } o;
        #pragma unroll
        for (int i = 0; i < 16; i++) {
            float4 cs = tab[i];      // {c0,s0,c1,s1} for pairs j=2i, 2i+1
            int j0 = 2 * i, j1 = 2 * i + 1;
            float a0 = bf2f(raw.u[j0]), b0 = bf2f(raw.u[j0 + 32]);
            float a1 = bf2f(raw.u[j1]), b1 = bf2f(raw.u[j1 + 32]);
            o.u[j0]      = f2bf(a0 * cs.x - b0 * cs.y);
            o.u[j0 + 32] = f2bf(b0 * cs.x + a0 * cs.y);
            o.u[j1]      = f2bf(a1 * cs.z - b1 * cs.w);
            o.u[j1 + 32] = f2bf(b1 * cs.z + a1 * cs.w);
        }
        #pragma unroll
        for (int i = 0; i < 8; i++) *(int4*)(dst + obase + 8 * i) = o.q[i];
    }
}

// ---------------- V transpose: Vb [BH,T,D] -> Vt [BH,D,T], key slot-permuted ----------------
__global__ __launch_bounds__(256) void vtr_k(const unsigned short* __restrict__ Vb,
                                             unsigned short* __restrict__ Vt) {
    __shared__ __align__(16) unsigned short Vsh[64][70];
    const int tid = threadIdx.x;
    const int tt = blockIdx.x;    // t-tile 0..31
    const int bh = blockIdx.y;    // 0..31
    const int sr = tid >> 2;
    const int sc = (tid & 3) * 16;
    const unsigned short* src = Vb + ((size_t)bh * TT + tt * 64 + sr) * 64 + sc;
    *(int4*)&Vsh[sr][sc]     = *(const int4*)src;
    *(int4*)&Vsh[sr][sc + 8] = *(const int4*)(src + 8);
    __syncthreads();
    const int dr = tid >> 2;
    const int tc = (tid & 3) * 16;
    unsigned short tv[16];
    #pragma unroll
    for (int i = 0; i < 16; i++) {
        int x = tc + i;
        int key = (x & ~15) + (x & 3) + ((x >> 2) & 1) * 8 + ((x >> 3) & 1) * 4;
        tv[i] = Vsh[key][dr];
    }
    size_t vo = ((size_t)bh * 64 + dr) * TT + tt * 64 + tc;
    *(int4*)(Vt + vo)     = *(int4*)&tv[0];
    *(int4*)(Vt + vo + 8) = *(int4*)&tv[8];
}

// ---------------- flash attention: 128-key macro-tiles, S^T trick, P in registers ----------------
__global__ __launch_bounds__(256, 3) void flash_k(const unsigned short* __restrict__ Qb,
                                                  const unsigned short* __restrict__ Kb,
                                                  const unsigned short* __restrict__ Vt,
                                                  unsigned short* __restrict__ O0,
                                                  unsigned short* __restrict__ O1,
                                                  float* __restrict__ L0, float* __restrict__ L1) {
    __shared__ __align__(16) unsigned short Ks[128][72];   // [key][d]        18.0 KB
    __shared__ __align__(16) unsigned short Vs[64][136];   // [d][key-slot]   17.0 KB
    const int tid  = threadIdx.x;
    const int wave = tid >> 6;
    const int lane = tid & 63;
    const int h    = lane >> 5;
    const int l32  = lane & 31;
    const int qt    = 15 - (blockIdx.x >> 6);   // LPT
    const int inner = blockIdx.x & 63;
    const int bh    = inner >> 1;
    const int split = inner & 1;
    const int q0 = qt * 128;
    const int qw = q0 + wave * 32 + l32;
    // staging maps
    const int kr = tid >> 1;            // 0..127 (key)
    const int kc = (tid & 1) * 32;      // shorts
    const int vr = tid >> 2;            // 0..63  (d)
    const int vc = (tid & 3) * 32;      // shorts

    bf16x8 qf[4];
    {
        const unsigned short* qp = Qb + ((size_t)bh * TT + qw) * 64 + h * 8;
        #pragma unroll
        for (int kk = 0; kk < 4; kk++) qf[kk] = *(const bf16x8*)(qp + kk * 16);
    }

    floatx16 accO[2];
    accO[0] = (floatx16)(0.f);
    accO[1] = (floatx16)(0.f);
    float lsum = 0.f;

    const int n128 = qt + 1;
    const int s0 = (n128 + 1) >> 1;
    const int m0 = split ? s0 : 0;
    const int m1 = split ? n128 : s0;
    const unsigned short* kbase = Kb + (size_t)bh * TT * 64;
    const unsigned short* vbase = Vt + (size_t)bh * 64 * TT;

    int4 kreg[4], vreg[4];
    if (m0 < m1) {
        const unsigned short* kp = kbase + ((size_t)(m0 * 128) + kr) * 64 + kc;
        const unsigned short* vp = vbase + (size_t)vr * TT + m0 * 128 + vc;
        #pragma unroll
        for (int i = 0; i < 4; i++) kreg[i] = *(const int4*)(kp + 8 * i);
        #pragma unroll
        for (int i = 0; i < 4; i++) vreg[i] = *(const int4*)(vp + 8 * i);
    }

    for (int m = m0; m < m1; m++) {
        __syncthreads();
        #pragma unroll
        for (int i = 0; i < 4; i++) *(int4*)&Ks[kr][kc + 8 * i] = kreg[i];
        #pragma unroll
        for (int i = 0; i < 4; i++) *(int4*)&Vs[vr][vc + 8 * i] = vreg[i];
        __syncthreads();
        if (m + 1 < m1) {
            const unsigned short* kp = kbase + ((size_t)((m + 1) * 128) + kr) * 64 + kc;
            const unsigned short* vp = vbase + (size_t)vr * TT + (m + 1) * 128 + vc;
            #pragma unroll
            for (int i = 0; i < 4; i++) kreg[i] = *(const int4*)(kp + 8 * i);
            #pragma unroll
            for (int i = 0; i < 4; i++) vreg[i] = *(const int4*)(vp + 8 * i);
        }

        const bool diag = (m == qt);
        #pragma unroll
        for (int sub = 0; sub < 2; sub++) {
            bf16x8 pfrag[4];
            #pragma unroll
            for (int mb = 0; mb < 2; mb++) {
                floatx16 sacc = (floatx16)(0.f);
                #pragma unroll
                for (int kk = 0; kk < 4; kk++) {
                    bf16x8 kf = *(const bf16x8*)&Ks[sub * 64 + 32 * mb + l32][kk * 16 + h * 8];
                    sacc = __builtin_amdgcn_mfma_f32_32x32x16_bf16(kf, qf[kk], sacc, 0, 0, 0);
                }
                float p[16];
                const int kmb = m * 128 + sub * 64 + 32 * mb + 4 * h;
                #pragma unroll
                for (int r = 0; r < 16; r++) {
                    float pv = __builtin_amdgcn_exp2f(sacc[r]);
                    if (diag) {
                        int ki = kmb + (r & 3) + 8 * (r >> 2);
                        if (ki > qw) pv = 0.f;
                    }
                    lsum += pv;
                    p[r] = pv;
                }
                #pragma unroll
                for (int hf = 0; hf < 2; hf++) {
                    union { bf16x8 v; unsigned u[4]; } pk;
                    #pragma unroll
                    for (int i = 0; i < 4; i++) {
                        unsigned ulo = __float_as_uint(p[hf * 8 + 2 * i]);
                        unsigned uhi = __float_as_uint(p[hf * 8 + 2 * i + 1]);
                        pk.u[i] = (ulo >> 16) | (uhi & 0xffff0000u);
                    }
                    pfrag[2 * mb + hf] = pk.v;
                }
            }
            #pragma unroll
            for (int mbo = 0; mbo < 2; mbo++) {
                #pragma unroll
                for (int kk = 0; kk < 4; kk++) {
                    bf16x8 vf = *(const bf16x8*)&Vs[32 * mbo + l32][sub * 64 + kk * 16 + h * 8];
                    accO[mbo] = __builtin_amdgcn_mfma_f32_32x32x16_bf16(vf, pfrag[kk], accO[mbo], 0, 0, 0);
                }
            }
        }
    }

    // epilogue: bf16 unnormalized partials (empty split stores zeros -> combine handles l1=0)
    lsum += __shfl_xor(lsum, 32);
    unsigned short* Op = split ? O1 : O0;
    float* Lp = split ? L1 : L0;
    if (lane < 32) Lp[(size_t)bh * TT + qw] = lsum;
    unsigned short* orow = Op + ((size_t)bh * TT + qw) * 64;
    #pragma unroll
    for (int mbo = 0; mbo < 2; mbo++)
        #pragma unroll
        for (int a = 0; a < 4; a++) {
            ushort4 o4;
            o4.x = f2bf(accO[mbo][4 * a + 0]);
            o4.y = f2bf(accO[mbo][4 * a + 1]);
            o4.z = f2bf(accO[mbo][4 * a + 2]);
            o4.w = f2bf(accO[mbo][4 * a + 3]);
            *(ushort4*)(orow + 32 * mbo + 8 * a + 4 * h) = o4;
        }
}

// ---------------- combine: Yb = (O0+O1)/(l0+l1), bf16 [B,T,C] ----------------
__global__ __launch_bounds__(256) void combine_k(const unsigned short* __restrict__ O0,
                                                 const unsigned short* __restrict__ O1,
                                                 const float* __restrict__ L0,
                                                 const float* __restrict__ L1,
                                                 unsigned short* __restrict__ Yb) {
    int idx = blockIdx.x * 256 + threadIdx.x;   // ushort4 index, 0..1048575
    int dg  = idx & 15;
    int row = idx >> 4;                          // bh*2048 + t
    float inv = 1.0f / (L0[row] + L1[row]);
    uint2 a = ((const uint2*)O0)[idx];
    uint2 b = ((const uint2*)O1)[idx];
    float a0 = __uint_as_float(a.x << 16),      b0 = __uint_as_float(b.x << 16);
    float a1 = __uint_as_float(a.x & 0xffff0000u), b1 = __uint_as_float(b.x & 0xffff0000u);
    float a2 = __uint_as_float(a.y << 16),      b2 = __uint_as_float(b.y << 16);
    float a3 = __uint_as_float(a.y & 0xffff0000u), b3 = __uint_as_float(b.y & 0xffff0000u);
    ushort4 o;
    o.x = f2bf((a0 + b0) * inv);
    o.y = f2bf((a1 + b1) * inv);
    o.z = f2bf((a2 + b2) * inv);
    o.w = f2bf((a3 + b3) * inv);
    int bh = row >> 11, t = row & (TT - 1);
    int bb = bh >> 4, hh = bh & 15;
    *(ushort4*)(Yb + ((size_t)(bb * TT + t)) * CC + hh * 64 + dg * 4) = o;
}

extern "C" void kernel_launch(void* const* d_in, const int* in_sizes, int n_in,
                              void* d_out, int out_size, void* d_ws, size_t ws_size,
                              hipStream_t stream) {
    (void)in_sizes; (void)n_in; (void)out_size; (void)ws_size;
    const float* x  = (const float*)d_in[0];
    const float* Wq = (const float*)d_in[1];
    const float* Wk = (const float*)d_in[2];
    const float* Wv = (const float*)d_in[3];
    const float* Wo = (const float*)d_in[4];
    float* out = (float*)d_out;
    char* ws = (char*)d_ws;

    unsigned short* xb    = (unsigned short*)(ws + 0);                      //  8 MB
    unsigned short* wqkvb = (unsigned short*)(ws + (8ull  << 20));          //  6 MB
    unsigned short* wob   = (unsigned short*)(ws + (14ull << 20));          //  2 MB
    unsigned short* Qb    = (unsigned short*)(ws + (16ull << 20));          //  8 MB [BH,T,D] (pre-scaled)
    unsigned short* Kb    = (unsigned short*)(ws + (24ull << 20));          //  8 MB [BH,T,D]
    unsigned short* Vb    = (unsigned short*)(ws + (32ull << 20));          //  8 MB [BH,T,D]
    unsigned short* Vt    = (unsigned short*)(ws + (40ull << 20));          //  8 MB [BH,D,T] slot-permuted
    unsigned short* Yb    = (unsigned short*)(ws + (48ull << 20));          //  8 MB
    unsigned short* O0    = (unsigned short*)(ws + (56ull << 20));          //  8 MB bf16 partials
    unsigned short* O1    = (unsigned short*)(ws + (64ull << 20));          //  8 MB
    float* L0 = (float*)(ws + (72ull << 20));                               // 256 KB
    float* L1 = (float*)(ws + (72ull << 20) + (256ull << 10));              // 256 KB
    float2* tabQ = (float2*)(ws + (73ull << 20));                           // 512 KB
    float2* tabK = (float2*)(ws + (73ull << 20) + (512ull << 10));          // 512 KB

    cast_all_k<<<8448, 256, 0, stream>>>(x, Wq, Wk, Wv, Wo, xb, wqkvb, wob, tabQ, tabK);
    gemm_qkv_k<<<768, 256, 0, stream>>>(xb, wqkvb, tabQ, tabK, Qb, Kb, Vb);
    vtr_k<<<dim3(32, 32), 256, 0, stream>>>(Vb, Vt);
    flash_k<<<1024, 256, 0, stream>>>(Qb, Kb, Vt, O0, O1, L0, L1);
    combine_k<<<4096, 256, 0, stream>>>(O0, O1, L0, L1, Yb);
    gemm128_k<<<256, 256, 0, stream>>>(Yb, wob, out, 1024, 1024);
}

// Round 8
// 180.409 us; speedup vs baseline: 1.2165x; 1.2165x over previous
//
#include <hip/hip_runtime.h>

// Problem constants
#define BB 2
#define TT 2048
#define CC 1024
#define NH 16
#define HD 64

typedef __attribute__((ext_vector_type(8))) short bf16x8;
typedef __attribute__((ext_vector_type(4))) float floatx4;
typedef __attribute__((ext_vector_type(16))) float floatx16;

__device__ __forceinline__ unsigned short f2bf(float f) {
    union { float f; unsigned int u; } v; v.f = f;
    unsigned int u = v.u;
    u = (u + 0x7fffu + ((u >> 16) & 1u)) >> 16;   // RNE
    return (unsigned short)u;
}
__device__ __forceinline__ float bf2f(unsigned short u) {
    return __uint_as_float((unsigned)u << 16);
}

typedef __attribute__((address_space(3))) unsigned char* lds_ptr_t;
typedef const __attribute__((address_space(1))) unsigned char* glob_ptr_t;
__device__ __forceinline__ void gll16(const void* g, void* l) {
    __builtin_amdgcn_global_load_lds((glob_ptr_t)g, (lds_ptr_t)l, 16, 0, 0);
}

// ---------------- fused cast fp32 -> bf16 + RoPE table build ----------------
__global__ __launch_bounds__(256) void cast_all_k(const float* __restrict__ x,
                                                  const float* __restrict__ wq,
                                                  const float* __restrict__ wk,
                                                  const float* __restrict__ wv,
                                                  const float* __restrict__ wo,
                                                  unsigned short* __restrict__ xb,
                                                  unsigned short* __restrict__ wqkvb,
                                                  unsigned short* __restrict__ wob,
                                                  float2* __restrict__ tabQ,
                                                  float2* __restrict__ tabK) {
    if (blockIdx.x >= 8192) {   // RoPE tables: 2048 t x 32 pairs
        int idx = (blockIdx.x - 8192) * 256 + threadIdx.x;   // 0..65535
        int t = idx >> 5, j = idx & 31;
        const float C1 = 0.41524101186092f;        // log2(10000)/32
        const float I2PI = 0.15915494309189535f;
        float rev = (float)t * (__builtin_amdgcn_exp2f(-(float)j * C1) * I2PI);
        rev -= floorf(rev);
        float ang = rev * 6.2831853071796f;
        float c = __cosf(ang), s = __sinf(ang);
        const float qs = 0.18033688011112f;        // (1/8)*log2(e), folded into Q table
        tabK[idx] = make_float2(c, s);
        tabQ[idx] = make_float2(c * qs, s * qs);
        return;
    }
    int i = blockIdx.x * 256 + threadIdx.x;   // float4 index
    const float* src;
    unsigned short* dst;
    if (i < 1048576) {
        src = x + (size_t)i * 4;
        dst = xb + (size_t)i * 4;
    } else {
        int w   = (i - 1048576) >> 18;        // 0..3
        int off = (i - 1048576) & 262143;
        const float* s0 = (w == 0) ? wq : (w == 1) ? wk : (w == 2) ? wv : wo;
        unsigned short* d0 = (w == 3) ? wob : (wqkvb + (size_t)w * 1048576);
        src = s0 + (size_t)off * 4;
        dst = d0 + (size_t)off * 4;
    }
    float4 v = *(const float4*)src;
    ushort4 o;
    o.x = f2bf(v.x); o.y = f2bf(v.y); o.z = f2bf(v.z); o.w = f2bf(v.w);
    *(ushort4*)dst = o;
}

// ---------------- out-proj GEMM: BK=64, XOR-swizzled LDS, XCD-swizzled grid ----------------
__global__ __launch_bounds__(256) void gemm128_k(const unsigned short* __restrict__ A,
                                                 const unsigned short* __restrict__ Bt,
                                                 float* __restrict__ C, int N, int K) {
    __shared__ __align__(16) unsigned short As[128][64];
    __shared__ __align__(16) unsigned short Bs[128][64];
    const int tid  = threadIdx.x;
    const int wave = tid >> 6;
    const int lane = tid & 63;
    const int quad = lane >> 4;
    const int l16  = lane & 15;
    const int sw   = l16 & 7;             // fragment-read XOR key
    const int wr = (wave >> 1) * 64;
    const int wc = (wave & 1) * 64;
    const int bid = blockIdx.x;
    const int xcd = bid & 7, sl = bid >> 3;          // sl 0..31
    const int row0 = (xcd * 4 + (sl >> 3)) * 128;
    const int col0 = (sl & 7) * 128;
    const int w8r = wave * 8 + (lane >> 3);
    const int cg  = ((lane & 7) ^ (lane >> 3)) * 8;  // global col (shorts)
    const int cl  = (lane & 7) * 8;                  // phys LDS col (shorts)

    const unsigned short* Ap = A  + (size_t)(row0 + w8r) * K + cg;
    const unsigned short* Bp = Bt + (size_t)(col0 + w8r) * K + cg;

    floatx4 acc[4][4];
    #pragma unroll
    for (int i = 0; i < 4; i++)
        #pragma unroll
        for (int j = 0; j < 4; j++) acc[i][j] = (floatx4){0.f, 0.f, 0.f, 0.f};

    for (int k0 = 0; k0 < K; k0 += 64) {
        __syncthreads();
        #pragma unroll
        for (int isu = 0; isu < 4; isu++) {
            gll16(Ap + (size_t)(isu * 32) * K + k0, &As[isu * 32 + w8r][cl]);
            gll16(Bp + (size_t)(isu * 32) * K + k0, &Bs[isu * 32 + w8r][cl]);
        }
        __syncthreads();
        #pragma unroll
        for (int kk = 0; kk < 2; kk++) {
            bf16x8 af[4], bfr[4];
            #pragma unroll
            for (int i = 0; i < 4; i++)
                af[i]  = *(const bf16x8*)&As[wr + 16 * i + l16][((kk * 4 + quad) ^ sw) * 8];
            #pragma unroll
            for (int j = 0; j < 4; j++)
                bfr[j] = *(const bf16x8*)&Bs[wc + 16 * j + l16][((kk * 4 + quad) ^ sw) * 8];
            #pragma unroll
            for (int i = 0; i < 4; i++)
                #pragma unroll
                for (int j = 0; j < 4; j++)
                    acc[i][j] = __builtin_amdgcn_mfma_f32_16x16x32_bf16(af[i], bfr[j], acc[i][j], 0, 0, 0);
        }
    }

    #pragma unroll
    for (int i = 0; i < 4; i++)
        #pragma unroll
        for (int j = 0; j < 4; j++)
            #pragma unroll
            for (int r = 0; r < 4; r++) {
                int row = row0 + wr + 16 * i + quad * 4 + r;
                int col = col0 + wc + 16 * j + l16;
                C[(size_t)row * N + col] = acc[i][j][r];
            }
}

// ---------------- QKV GEMM: BK=64, XOR-swizzled LDS, table-RoPE LDS-bounce epilogue ----------------
__global__ __launch_bounds__(256) void gemm_qkv_k(const unsigned short* __restrict__ A,
                                                  const unsigned short* __restrict__ Bt,
                                                  const float2* __restrict__ tabQ,
                                                  const float2* __restrict__ tabK,
                                                  unsigned short* __restrict__ Qb,
                                                  unsigned short* __restrict__ Kb,
                                                  unsigned short* __restrict__ Vb) {
    __shared__ __align__(16) unsigned short SMEM[128 * 128];   // 32 KB: As+Bs in loop, Eb in epilogue
    unsigned short (*As)[64] = (unsigned short(*)[64])SMEM;
    unsigned short (*Bs)[64] = (unsigned short(*)[64])(SMEM + 128 * 64);
    unsigned short (*Eb)[128] = (unsigned short(*)[128])SMEM;
    const int K = 1024;
    const int tid  = threadIdx.x;
    const int wave = tid >> 6;
    const int lane = tid & 63;
    const int quad = lane >> 4;
    const int l16  = lane & 15;
    const int sw   = l16 & 7;
    const int wr = (wave >> 1) * 64;
    const int wc = (wave & 1) * 64;
    const int bid = blockIdx.x;
    const int xcd = bid & 7, sl = bid >> 3;          // sl 0..95
    const int row0 = (xcd * 4 + sl / 24) * 128;
    const int col0 = (sl % 24) * 128;
    const int w8r = wave * 8 + (lane >> 3);
    const int cg  = ((lane & 7) ^ (lane >> 3)) * 8;
    const int cl  = (lane & 7) * 8;

    const unsigned short* Ap = A  + (size_t)(row0 + w8r) * K + cg;
    const unsigned short* Bp = Bt + (size_t)(col0 + w8r) * K + cg;

    floatx4 acc[4][4];
    #pragma unroll
    for (int i = 0; i < 4; i++)
        #pragma unroll
        for (int j = 0; j < 4; j++) acc[i][j] = (floatx4){0.f, 0.f, 0.f, 0.f};

    for (int k0 = 0; k0 < K; k0 += 64) {
        __syncthreads();
        #pragma unroll
        for (int isu = 0; isu < 4; isu++) {
            gll16(Ap + (size_t)(isu * 32) * K + k0, &As[isu * 32 + w8r][cl]);
            gll16(Bp + (size_t)(isu * 32) * K + k0, &Bs[isu * 32 + w8r][cl]);
        }
        __syncthreads();
        #pragma unroll
        for (int kk = 0; kk < 2; kk++) {
            bf16x8 af[4], bfr[4];
            #pragma unroll
            for (int i = 0; i < 4; i++)
                af[i]  = *(const bf16x8*)&As[wr + 16 * i + l16][((kk * 4 + quad) ^ sw) * 8];
            #pragma unroll
            for (int j = 0; j < 4; j++)
                bfr[j] = *(const bf16x8*)&Bs[wc + 16 * j + l16][((kk * 4 + quad) ^ sw) * 8];
            #pragma unroll
            for (int i = 0; i < 4; i++)
                #pragma unroll
                for (int j = 0; j < 4; j++)
                    acc[i][j] = __builtin_amdgcn_mfma_f32_16x16x32_bf16(af[i], bfr[j], acc[i][j], 0, 0, 0);
        }
    }

    // ---- Phase 1: acc -> Eb (bf16), XOR-granule swizzle ----
    __syncthreads();
    #pragma unroll
    for (int i = 0; i < 4; i++)
        #pragma unroll
        for (int j = 0; j < 4; j++)
            #pragma unroll
            for (int r = 0; r < 4; r++) {
                int erow = wr + 16 * i + quad * 4 + r;
                int col  = wc + 16 * j + l16;
                int pcol = (((col >> 3) ^ (erow & 15)) << 3) | (col & 7);
                Eb[erow][pcol] = f2bf(acc[i][j][r]);
            }
    __syncthreads();

    // ---- Phase 2: row-wise readback, RoPE via table, coalesced stores ----
    const int row  = tid >> 1;            // 0..127
    const int half = tid & 1;
    const int grow = row0 + row;
    const int t    = grow & (TT - 1);
    const int bb   = grow >> 11;
    const int sect = col0 >> 10;                        // 0=Q,1=K,2=V
    const int hh   = ((col0 & 1023) >> 6) + half;       // head
    union { int4 q[8]; unsigned short u[64]; } raw;
    #pragma unroll
    for (int i = 0; i < 8; i++) {
        int pg = (half * 8 + i) ^ (row & 15);
        raw.q[i] = *(const int4*)&Eb[row][pg << 3];
    }
    size_t obase = ((size_t)(bb * NH + hh) * TT + t) * 64;
    if (sect == 2) {
        #pragma unroll
        for (int i = 0; i < 8; i++) *(int4*)(Vb + obase + 8 * i) = raw.q[i];
    } else {
        const float4* tab = (const float4*)((sect ? tabK : tabQ) + (size_t)t * 32);
        unsigned short* dst = sect ? Kb : Qb;
        union { int4 q[8]; unsigned short u[64]; } o;
        #pragma unroll
        for (int i = 0; i < 16; i++) {
            float4 cs = tab[i];      // {c0,s0,c1,s1} for pairs j=2i, 2i+1
            int j0 = 2 * i, j1 = 2 * i + 1;
            float a0 = bf2f(raw.u[j0]), b0 = bf2f(raw.u[j0 + 32]);
            float a1 = bf2f(raw.u[j1]), b1 = bf2f(raw.u[j1 + 32]);
            o.u[j0]      = f2bf(a0 * cs.x - b0 * cs.y);
            o.u[j0 + 32] = f2bf(b0 * cs.x + a0 * cs.y);
            o.u[j1]      = f2bf(a1 * cs.z - b1 * cs.w);
            o.u[j1 + 32] = f2bf(b1 * cs.z + a1 * cs.w);
        }
        #pragma unroll
        for (int i = 0; i < 8; i++) *(int4*)(dst + obase + 8 * i) = o.q[i];
    }
}

// ---------------- V transpose: Vb [BH,T,D] -> Vt [BH,D,T], key slot-permuted ----------------
__global__ __launch_bounds__(256) void vtr_k(const unsigned short* __restrict__ Vb,
                                             unsigned short* __restrict__ Vt) {
    __shared__ __align__(16) unsigned short Vsh[64][70];
    const int tid = threadIdx.x;
    const int tt = blockIdx.x;    // t-tile 0..31
    const int bh = blockIdx.y;    // 0..31
    const int sr = tid >> 2;
    const int sc = (tid & 3) * 16;
    const unsigned short* src = Vb + ((size_t)bh * TT + tt * 64 + sr) * 64 + sc;
    *(int4*)&Vsh[sr][sc]     = *(const int4*)src;
    *(int4*)&Vsh[sr][sc + 8] = *(const int4*)(src + 8);
    __syncthreads();
    const int dr = tid >> 2;
    const int tc = (tid & 3) * 16;
    unsigned short tv[16];
    #pragma unroll
    for (int i = 0; i < 16; i++) {
        int x = tc + i;
        int key = (x & ~15) + (x & 3) + ((x >> 2) & 1) * 8 + ((x >> 3) & 1) * 4;
        tv[i] = Vsh[key][dr];
    }
    size_t vo = ((size_t)bh * 64 + dr) * TT + tt * 64 + tc;
    *(int4*)(Vt + vo)     = *(int4*)&tv[0];
    *(int4*)(Vt + vo + 8) = *(int4*)&tv[8];
}

// ---------------- flash attention: S^T = K Q^T via 32x32x16 MFMA, P in registers, bf16 partials ----------------
// (round-6-proven version: 64-key tiles, (256,4), no scratch spill)
__global__ __launch_bounds__(256, 4) void flash_k(const unsigned short* __restrict__ Qb,
                                                  const unsigned short* __restrict__ Kb,
                                                  const unsigned short* __restrict__ Vt,
                                                  unsigned short* __restrict__ O0,
                                                  unsigned short* __restrict__ O1,
                                                  float* __restrict__ L0, float* __restrict__ L1) {
    __shared__ __align__(16) unsigned short Ks[64][72];   // [key][d]
    __shared__ __align__(16) unsigned short Vs[64][72];   // [d][key-slot] (sigma-permuted)
    const int tid  = threadIdx.x;
    const int wave = tid >> 6;
    const int lane = tid & 63;
    const int h    = lane >> 5;
    const int l32  = lane & 31;
    const int qt    = 15 - (blockIdx.x >> 6);   // LPT
    const int inner = blockIdx.x & 63;
    const int bh    = inner >> 1;
    const int split = inner & 1;
    const int q0 = qt * 128;
    const int qw = q0 + wave * 32 + l32;
    const int sr = tid >> 2;
    const int sc = (tid & 3) * 16;

    bf16x8 qf[4];
    {
        const unsigned short* qp = Qb + ((size_t)bh * TT + qw) * 64 + h * 8;
        #pragma unroll
        for (int kk = 0; kk < 4; kk++) qf[kk] = *(const bf16x8*)(qp + kk * 16);
    }

    floatx16 accO[2];
    accO[0] = (floatx16)(0.f);
    accO[1] = (floatx16)(0.f);
    float lsum = 0.f;

    const int kt0 = split * (qt + 1);
    const int kt1 = kt0 + qt + 1;
    const unsigned short* kbase = Kb + (size_t)bh * TT * 64;
    const unsigned short* vbase = Vt + (size_t)bh * 64 * TT;

    const unsigned short* kp = kbase + ((size_t)(kt0 * 64) + sr) * 64 + sc;
    const unsigned short* vp = vbase + (size_t)sr * TT + kt0 * 64 + sc;
    int4 ka = *(const int4*)kp, kb2 = *(const int4*)(kp + 8);
    int4 va = *(const int4*)vp, vb2 = *(const int4*)(vp + 8);

    for (int kt = kt0; kt < kt1; kt++) {
        __syncthreads();
        *(int4*)&Ks[sr][sc]     = ka;
        *(int4*)&Ks[sr][sc + 8] = kb2;
        *(int4*)&Vs[sr][sc]     = va;
        *(int4*)&Vs[sr][sc + 8] = vb2;
        __syncthreads();
        if (kt + 1 < kt1) {
            const unsigned short* kp2 = kbase + ((size_t)((kt + 1) * 64) + sr) * 64 + sc;
            const unsigned short* vp2 = vbase + (size_t)sr * TT + (kt + 1) * 64 + sc;
            ka  = *(const int4*)kp2; kb2 = *(const int4*)(kp2 + 8);
            va  = *(const int4*)vp2; vb2 = *(const int4*)(vp2 + 8);
        }

        const bool diag = (kt >= 2 * qt);
        bf16x8 pfrag[4];

        #pragma unroll
        for (int mb = 0; mb < 2; mb++) {
            floatx16 sacc = (floatx16)(0.f);
            #pragma unroll
            for (int kk = 0; kk < 4; kk++) {
                bf16x8 kf = *(const bf16x8*)&Ks[32 * mb + l32][kk * 16 + h * 8];
                sacc = __builtin_amdgcn_mfma_f32_32x32x16_bf16(kf, qf[kk], sacc, 0, 0, 0);
            }
            float p[16];
            const int kmb = kt * 64 + 32 * mb + 4 * h;
            #pragma unroll
            for (int r = 0; r < 16; r++) {
                float pv = __builtin_amdgcn_exp2f(sacc[r]);
                if (diag) {
                    int ki = kmb + (r & 3) + 8 * (r >> 2);
                    if (ki > qw) pv = 0.f;
                }
                lsum += pv;
                p[r] = pv;
            }
            #pragma unroll
            for (int half = 0; half < 2; half++) {
                union { bf16x8 v; unsigned u[4]; } pk;
                #pragma unroll
                for (int i = 0; i < 4; i++) {
                    unsigned ulo = __float_as_uint(p[half * 8 + 2 * i]);
                    unsigned uhi = __float_as_uint(p[half * 8 + 2 * i + 1]);
                    pk.u[i] = (ulo >> 16) | (uhi & 0xffff0000u);
                }
                pfrag[2 * mb + half] = pk.v;
            }
        }

        #pragma unroll
        for (int mbo = 0; mbo < 2; mbo++) {
            #pragma unroll
            for (int kk = 0; kk < 4; kk++) {
                bf16x8 vf = *(const bf16x8*)&Vs[32 * mbo + l32][kk * 16 + h * 8];
                accO[mbo] = __builtin_amdgcn_mfma_f32_32x32x16_bf16(vf, pfrag[kk], accO[mbo], 0, 0, 0);
            }
        }
    }

    // epilogue: bf16 unnormalized partials
    lsum += __shfl_xor(lsum, 32);
    unsigned short* Op = split ? O1 : O0;
    float* Lp = split ? L1 : L0;
    if (lane < 32) Lp[(size_t)bh * TT + qw] = lsum;
    unsigned short* orow = Op + ((size_t)bh * TT + qw) * 64;
    #pragma unroll
    for (int mbo = 0; mbo < 2; mbo++)
        #pragma unroll
        for (int a = 0; a < 4; a++) {
            ushort4 o4;
            o4.x = f2bf(accO[mbo][4 * a + 0]);
            o4.y = f2bf(accO[mbo][4 * a + 1]);
            o4.z = f2bf(accO[mbo][4 * a + 2]);
            o4.w = f2bf(accO[mbo][4 * a + 3]);
            *(ushort4*)(orow + 32 * mbo + 8 * a + 4 * h) = o4;
        }
}

// ---------------- combine: Yb = (O0+O1)/(l0+l1), bf16 [B,T,C] ----------------
__global__ __launch_bounds__(256) void combine_k(const unsigned short* __restrict__ O0,
                                                 const unsigned short* __restrict__ O1,
                                                 const float* __restrict__ L0,
                                                 const float* __restrict__ L1,
                                                 unsigned short* __restrict__ Yb) {
    int idx = blockIdx.x * 256 + threadIdx.x;   // ushort4 index, 0..1048575
    int dg  = idx & 15;
    int row = idx >> 4;                          // bh*2048 + t
    float inv = 1.0f / (L0[row] + L1[row]);
    uint2 a = ((const uint2*)O0)[idx];
    uint2 b = ((const uint2*)O1)[idx];
    float a0 = __uint_as_float(a.x << 16),      b0 = __uint_as_float(b.x << 16);
    float a1 = __uint_as_float(a.x & 0xffff0000u), b1 = __uint_as_float(b.x & 0xffff0000u);
    float a2 = __uint_as_float(a.y << 16),      b2 = __uint_as_float(b.y << 16);
    float a3 = __uint_as_float(a.y & 0xffff0000u), b3 = __uint_as_float(b.y & 0xffff0000u);
    ushort4 o;
    o.x = f2bf((a0 + b0) * inv);
    o.y = f2bf((a1 + b1) * inv);
    o.z = f2bf((a2 + b2) * inv);
    o.w = f2bf((a3 + b3) * inv);
    int bh = row >> 11, t = row & (TT - 1);
    int bb = bh >> 4, hh = bh & 15;
    *(ushort4*)(Yb + ((size_t)(bb * TT + t)) * CC + hh * 64 + dg * 4) = o;
}

extern "C" void kernel_launch(void* const* d_in, const int* in_sizes, int n_in,
                              void* d_out, int out_size, void* d_ws, size_t ws_size,
                              hipStream_t stream) {
    (void)in_sizes; (void)n_in; (void)out_size; (void)ws_size;
    const float* x  = (const float*)d_in[0];
    const float* Wq = (const float*)d_in[1];
    const float* Wk = (const float*)d_in[2];
    const float* Wv = (const float*)d_in[3];
    const float* Wo = (const float*)d_in[4];
    float* out = (float*)d_out;
    char* ws = (char*)d_ws;

    unsigned short* xb    = (unsigned short*)(ws + 0);                      //  8 MB
    unsigned short* wqkvb = (unsigned short*)(ws + (8ull  << 20));          //  6 MB
    unsigned short* wob   = (unsigned short*)(ws + (14ull << 20));          //  2 MB
    unsigned short* Qb    = (unsigned short*)(ws + (16ull << 20));          //  8 MB [BH,T,D] (pre-scaled)
    unsigned short* Kb    = (unsigned short*)(ws + (24ull << 20));          //  8 MB [BH,T,D]
    unsigned short* Vb    = (unsigned short*)(ws + (32ull << 20));          //  8 MB [BH,T,D]
    unsigned short* Vt    = (unsigned short*)(ws + (40ull << 20));          //  8 MB [BH,D,T] slot-permuted
    unsigned short* Yb    = (unsigned short*)(ws + (48ull << 20));          //  8 MB
    unsigned short* O0    = (unsigned short*)(ws + (56ull << 20));          //  8 MB bf16 partials
    unsigned short* O1    = (unsigned short*)(ws + (64ull << 20));          //  8 MB
    float* L0 = (float*)(ws + (72ull << 20));                               // 256 KB
    float* L1 = (float*)(ws + (72ull << 20) + (256ull << 10));              // 256 KB
    float2* tabQ = (float2*)(ws + (73ull << 20));                           // 512 KB
    float2* tabK = (float2*)(ws + (73ull << 20) + (512ull << 10));          // 512 KB

    cast_all_k<<<8448, 256, 0, stream>>>(x, Wq, Wk, Wv, Wo, xb, wqkvb, wob, tabQ, tabK);
    gemm_qkv_k<<<768, 256, 0, stream>>>(xb, wqkvb, tabQ, tabK, Qb, Kb, Vb);
    vtr_k<<<dim3(32, 32), 256, 0, stream>>>(Vb, Vt);
    flash_k<<<1024, 256, 0, stream>>>(Qb, Kb, Vt, O0, O1, L0, L1);
    combine_k<<<4096, 256, 0, stream>>>(O0, O1, L0, L1, Yb);
    gemm128_k<<<256, 256, 0, stream>>>(Yb, wob, out, 1024, 1024);
}